// Round 10
// baseline (145.270 us; speedup 1.0000x reference)
//
#include <hip/hip_runtime.h>

// Problem constants (from reference)
#define BB      2
#define CC      256
#define HH      384
#define WW      384
#define N_ACT   16384
#define GRID_N  192                  // index grid; coord = 2*idx (OFFSET=0, STRIDE=2)
#define NCELL   (GRID_N * GRID_N)
#define PLANE_F4 ((HH * WW) / 4)     // 36864 float4 per (b,c) plane
#define ROW_F4   (WW / 4)            // 96 float4 per row
#define EVEN_SLOTS 18432             // even-row float4 per plane
#define ODD_HALF   9216              // odd slots handled per thread-pass
#define B_BLK_PER_PLANE 72           // merge kernel: 18432/256
#define A_BLK_PER_PLANE 36           // copy kernel: 9216/256 (2 f4/thread)
#define NXCD    8

// Native clang vector type — required by __builtin_nontemporal_load/store.
typedef float fx4 __attribute__((ext_vector_type(4)));

// --- Kernel 1: winner[cell] = max k writing to that cell (numpy last-wins) --
__global__ void winner_scatter_kernel(const int2* __restrict__ idx,
                                      int* __restrict__ winner) {
    int k = blockIdx.x * blockDim.x + threadIdx.x;
    if (k < N_ACT) {
        int2 p = idx[k];                        // p.x = iy, p.y = ix
        atomicMax(&winner[p.x * GRID_N + p.y], k);
    }
}

// --- Kernel A: pure copy of all ODD rows (no gather chain at all) -----------
// 2 float4 per thread, two contiguous half-plane segments. Pure stream:
// should run at copy-rate (~6.5 TB/s).
__global__ void copy_odd_kernel(const fx4* __restrict__ orig,
                                fx4* __restrict__ out) {
    int L = blockIdx.x;
    int p = L / A_BLK_PER_PLANE;                  // plane 0..511
    int j = L - p * A_BLK_PER_PLANE;              // 0..35
    int s = j * 256 + threadIdx.x;                // odd slot 0..9215
    int gy  = s / ROW_F4;                         // 0..95
    int col = s - gy * ROW_F4;
    int a  = p * PLANE_F4 + (2 * gy + 1) * ROW_F4 + col;  // odd row 2gy+1
    int a2 = a + PLANE_F4 / 2;                    // odd row 2(gy+96)+1

    fx4 v1 = __builtin_nontemporal_load(&orig[a]);
    fx4 v2 = __builtin_nontemporal_load(&orig[a2]);
    __builtin_nontemporal_store(v1, &out[a]);
    __builtin_nontemporal_store(v2, &out[a2]);
}

// --- Kernel B: merge EVEN rows (r8's proven gather path, XCD-local planes) --
// All 72 blocks of plane p share L%8 -> one XCD; the plane's 64KB x-slice
// and the winner map stay in that XCD's L2, so gathers are warm-L2 hits.
__global__ void merge_even_kernel(const fx4* __restrict__ orig,
                                  const float* __restrict__ x,
                                  const int* __restrict__ winner,
                                  fx4* __restrict__ out) {
    int L   = blockIdx.x;
    int xcd = L & (NXCD - 1);
    int g   = L >> 3;                             // 0..4607
    int p   = (g / B_BLK_PER_PLANE) * NXCD + xcd; // plane 0..511
    int j   = g % B_BLK_PER_PLANE;                // 0..71

    int q   = j * 256 + threadIdx.x;              // even slot 0..18431
    int gy  = q / ROW_F4;                         // 0..191
    int col = q - gy * ROW_F4;                    // 0..95

    int base = p * PLANE_F4 + (gy * 2) * ROW_F4 + col;   // even row 2gy

    const int2* wrow2 = reinterpret_cast<const int2*>(winner + gy * GRID_N);
    int2 w = wrow2[col];                          // cells gx=2col, 2col+1
    fx4 ve = __builtin_nontemporal_load(&orig[base]);

    if (w.x >= 0 || w.y >= 0) {
        const float* xp = x + p * N_ACT;
        if (w.x >= 0) ve[0] = xp[w.x];
        if (w.y >= 0) ve[2] = xp[w.y];
    }

    __builtin_nontemporal_store(ve, &out[base]);
}

extern "C" void kernel_launch(void* const* d_in, const int* in_sizes, int n_in,
                              void* d_out, int out_size, void* d_ws, size_t ws_size,
                              hipStream_t stream) {
    const float* x    = (const float*)d_in[0];   // [B, C, N_ACT]
    const float* orig = (const float*)d_in[1];   // [B, C, H, W]
    const int*   idx  = (const int*)d_in[2];     // [N_ACT, 2]
    float*       out  = (float*)d_out;           // [B, C, H, W]
    int*         winner = (int*)d_ws;            // NCELL ints = 147456 B

    // 1. winner map = -1 (0xFF bytes) — async memset is graph-capturable
    (void)hipMemsetAsync(winner, 0xFF, NCELL * sizeof(int), stream);
    // 2. last-write-wins via atomicMax over k
    winner_scatter_kernel<<<dim3((N_ACT + 255) / 256), dim3(256), 0, stream>>>(
        (const int2*)idx, winner);
    // 3a. pure-copy of odd rows (no dependent chain)
    copy_odd_kernel<<<dim3(BB * CC * A_BLK_PER_PLANE), dim3(256), 0, stream>>>(
        (const fx4*)orig, (fx4*)out);
    // 3b. gather-merge of even rows, XCD-local planes
    merge_even_kernel<<<dim3(BB * CC * B_BLK_PER_PLANE), dim3(256), 0, stream>>>(
        (const fx4*)orig, x, winner, (fx4*)out);
}

// Round 11
// 134.154 us; speedup vs baseline: 1.0829x; 1.0829x over previous
//
#include <hip/hip_runtime.h>

// Problem constants (from reference)
#define BB      2
#define CC      256
#define HH      384
#define WW      384
#define N_ACT   16384
#define GRID_N  192                  // index grid; coord = 2*idx (OFFSET=0, STRIDE=2)
#define NCELL   (GRID_N * GRID_N)
#define PLANE_F4 ((HH * WW) / 4)     // 36864 float4 per (b,c) plane
#define ROW_F4   (WW / 4)            // 96 float4 per row
#define PAIRS_PER_PLANE (PLANE_F4 / 2)   // 18432 row-pair float4 slots
#define BLK_PER_PLANE (PAIRS_PER_PLANE / 256)  // 72
#define NXCD    8
#define X_F4    (N_ACT / 4)          // 4096 float4 per plane x-slice
#define PF_PER_BLK 57                // ceil(4096/72)

// Native clang vector type — required by __builtin_nontemporal_load/store.
typedef float fx4 __attribute__((ext_vector_type(4)));

// --- Kernel 1: winner[cell] = max k writing to that cell (numpy last-wins) --
__global__ void winner_scatter_kernel(const int2* __restrict__ idx,
                                      int* __restrict__ winner) {
    int k = blockIdx.x * blockDim.x + threadIdx.x;
    if (k < N_ACT) {
        int2 p = idx[k];                        // p.x = iy, p.y = ix
        atomicMax(&winner[p.x * GRID_N + p.y], k);
    }
}

// --- Kernel 2: fused copy + patch (r8 body) + linear L2-prefetch of x -------
// XCD-local planes: all 72 blocks of plane p share L%8 == p%8 -> one XCD;
// plane's x-slice + winner map stay in that XCD's L2.
// NEW: block j linearly prefetches chunk j of its plane's 64KB x-slice
// (lanes 0..56, one float4 each) so the ~random gathers below hit L2
// instead of issuing cold random 128B HBM reads interleaved into the
// linear stream. Loads issue at the top; the empty-asm keep-alive sink sits
// AFTER the stores so no extra wait blocks the main work.
__global__ void scatter_main_kernel(const fx4* __restrict__ orig,
                                    const float* __restrict__ x,
                                    const int* __restrict__ winner,
                                    fx4* __restrict__ out) {
    int L   = blockIdx.x;
    int xcd = L & (NXCD - 1);
    int g   = L >> 3;                             // 0..4607
    int p   = (g / BLK_PER_PLANE) * NXCD + xcd;   // plane 0..511
    int j   = g % BLK_PER_PLANE;                  // block-in-plane 0..71

    // Linear prefetch of this plane's x slice into L2 (cached, NOT nt).
    fx4 pfv = {0.f, 0.f, 0.f, 0.f};
    int pf = j * PF_PER_BLK + threadIdx.x;
    if (threadIdx.x < PF_PER_BLK && pf < X_F4)
        pfv = reinterpret_cast<const fx4*>(x + p * N_ACT)[pf];

    int q   = j * 256 + threadIdx.x;              // row-pair slot 0..18431
    int gy  = q / ROW_F4;                         // grid row 0..191
    int col = q - gy * ROW_F4;                    // float4 col 0..95

    int base = p * PLANE_F4 + (gy * 2) * ROW_F4 + col;   // even row slot

    // Independent loads issued together: winner pair + two stream float4s.
    const int2* wrow2 = reinterpret_cast<const int2*>(winner + gy * GRID_N);
    int2 w = wrow2[col];                          // cells gx=2col, 2col+1
    fx4 ve = __builtin_nontemporal_load(&orig[base]);
    fx4 vo = __builtin_nontemporal_load(&orig[base + ROW_F4]);

    if (w.x >= 0 || w.y >= 0) {
        const float* xp = x + p * N_ACT;
        if (w.x >= 0) ve[0] = xp[w.x];
        if (w.y >= 0) ve[2] = xp[w.y];
    }

    __builtin_nontemporal_store(ve, &out[base]);
    __builtin_nontemporal_store(vo, &out[base + ROW_F4]);

    // Keep the prefetch load alive (anti-DCE); waitcnt lands here, after all
    // real work has issued.
    asm volatile("" :: "v"(pfv[0]), "v"(pfv[1]), "v"(pfv[2]), "v"(pfv[3]));
}

extern "C" void kernel_launch(void* const* d_in, const int* in_sizes, int n_in,
                              void* d_out, int out_size, void* d_ws, size_t ws_size,
                              hipStream_t stream) {
    const float* x    = (const float*)d_in[0];   // [B, C, N_ACT]
    const float* orig = (const float*)d_in[1];   // [B, C, H, W]
    const int*   idx  = (const int*)d_in[2];     // [N_ACT, 2]
    float*       out  = (float*)d_out;           // [B, C, H, W]
    int*         winner = (int*)d_ws;            // NCELL ints = 147456 B

    // 1. winner map = -1 (0xFF bytes) — async memset is graph-capturable
    (void)hipMemsetAsync(winner, 0xFF, NCELL * sizeof(int), stream);
    // 2. last-write-wins via atomicMax over k
    winner_scatter_kernel<<<dim3((N_ACT + 255) / 256), dim3(256), 0, stream>>>(
        (const int2*)idx, winner);
    // 3. fused copy + patch, XCD-local planes + linear x prefetch
    scatter_main_kernel<<<dim3(BB * CC * BLK_PER_PLANE), dim3(256), 0, stream>>>(
        (const fx4*)orig, x, winner, (fx4*)out);
}

// Round 12
// 128.283 us; speedup vs baseline: 1.1324x; 1.0458x over previous
//
#include <hip/hip_runtime.h>

// Problem constants (from reference)
#define BB      2
#define CC      256
#define HH      384
#define WW      384
#define N_ACT   16384
#define GRID_N  192                  // index grid; coord = 2*idx (OFFSET=0, STRIDE=2)
#define NCELL   (GRID_N * GRID_N)
#define PLANE_F4 ((HH * WW) / 4)     // 36864 float4 per (b,c) plane
#define ROW_F4   (WW / 4)            // 96 float4 per row
#define PAIRS_PER_PLANE (PLANE_F4 / 2)   // 18432 row-pair float4 slots
#define BLK_PER_PLANE (PAIRS_PER_PLANE / 256)  // 72
#define NXCD    8

// Native clang vector type — required by __builtin_nontemporal_load/store.
typedef float fx4 __attribute__((ext_vector_type(4)));

// --- Kernel 1: winner[cell] = max k writing to that cell (numpy last-wins) --
__global__ void winner_scatter_kernel(const int2* __restrict__ idx,
                                      int* __restrict__ winner) {
    int k = blockIdx.x * blockDim.x + threadIdx.x;
    if (k < N_ACT) {
        int2 p = idx[k];                        // p.x = iy, p.y = ix
        atomicMax(&winner[p.x * GRID_N + p.y], k);
    }
}

// --- Kernel 2: fused copy + patch, r3 structure + XCD-local planes ----------
// All 72 blocks of plane p share L%8 == p%8, so under round-robin block->XCD
// dispatch each plane's 64KB x-slice lands in exactly one XCD's L2; gathers
// become warm-L2 hits instead of L3 round-trips replicated on 8 XCDs.
// NT loads (orig read-once) + NT stores (r3-vs-r5: NT stores were faster).
// Branchy exec-masked gathers: only ~35% of cells are active; clamped
// unconditional gathers (r7) cost ~2.9x gather traffic — don't.
// NOTE: this exact body is a sharp local optimum — r4/r5/r9/r10/r11 each
// perturbed one aspect (tile size, store caching, issue order, kernel split,
// prefetch) and ALL regressed. Change nothing without a new counter theory.
__global__ void scatter_main_kernel(const fx4* __restrict__ orig,
                                    const float* __restrict__ x,
                                    const int* __restrict__ winner,
                                    fx4* __restrict__ out) {
    int L   = blockIdx.x;
    int xcd = L & (NXCD - 1);
    int g   = L >> 3;                             // 0..4607
    int p   = (g / BLK_PER_PLANE) * NXCD + xcd;   // plane 0..511
    int j   = g % BLK_PER_PLANE;                  // block-in-plane 0..71

    int q   = j * 256 + threadIdx.x;              // row-pair slot 0..18431
    int gy  = q / ROW_F4;                         // grid row 0..191
    int col = q - gy * ROW_F4;                    // float4 col 0..95

    int base = p * PLANE_F4 + (gy * 2) * ROW_F4 + col;   // even row slot

    // Independent loads issued together: winner pair + two stream float4s.
    const int2* wrow2 = reinterpret_cast<const int2*>(winner + gy * GRID_N);
    int2 w = wrow2[col];                          // cells gx=2col, 2col+1
    fx4 ve = __builtin_nontemporal_load(&orig[base]);
    fx4 vo = __builtin_nontemporal_load(&orig[base + ROW_F4]);

    if (w.x >= 0 || w.y >= 0) {
        const float* xp = x + p * N_ACT;
        if (w.x >= 0) ve[0] = xp[w.x];
        if (w.y >= 0) ve[2] = xp[w.y];
    }

    __builtin_nontemporal_store(ve, &out[base]);
    __builtin_nontemporal_store(vo, &out[base + ROW_F4]);
}

extern "C" void kernel_launch(void* const* d_in, const int* in_sizes, int n_in,
                              void* d_out, int out_size, void* d_ws, size_t ws_size,
                              hipStream_t stream) {
    const float* x    = (const float*)d_in[0];   // [B, C, N_ACT]
    const float* orig = (const float*)d_in[1];   // [B, C, H, W]
    const int*   idx  = (const int*)d_in[2];     // [N_ACT, 2]
    float*       out  = (float*)d_out;           // [B, C, H, W]
    int*         winner = (int*)d_ws;            // NCELL ints = 147456 B

    // 1. winner map = -1 (0xFF bytes) — async memset is graph-capturable
    (void)hipMemsetAsync(winner, 0xFF, NCELL * sizeof(int), stream);
    // 2. last-write-wins via atomicMax over k
    winner_scatter_kernel<<<dim3((N_ACT + 255) / 256), dim3(256), 0, stream>>>(
        (const int2*)idx, winner);
    // 3. fused copy + patch, XCD-local planes
    scatter_main_kernel<<<dim3(BB * CC * BLK_PER_PLANE), dim3(256), 0, stream>>>(
        (const fx4*)orig, x, winner, (fx4*)out);
}